// Round 1
// baseline (291.573 us; speedup 1.0000x reference)
//
#include <hip/hip_runtime.h>
#include <math.h>

// Problem constants (B=2, H=W=32, DM=192, DS=16, RK=12, DI=384)
#define TOK 2048
#define DMOD 192
#define DI 384
#define DS 16
#define RK 12
#define NCOL 56     // 2*RK + 2*DS
#define HH 32
#define WW 32
#define BB 2

__device__ __forceinline__ float gelu_exact(float x) {
    return 0.5f * x * (1.0f + erff(x * 0.70710678118654752f));
}
__device__ __forceinline__ float softplus_f(float x) {
    return (x > 20.0f) ? x : log1pf(expf(x));
}

// K1: h = gelu(x @ W_in + b_in)   (2048,192)@(192,384)
__global__ void k1_inproj(const float* __restrict__ x, const float* __restrict__ W_in,
                          const float* __restrict__ b_in, float* __restrict__ h) {
    int n = blockIdx.x * 128 + threadIdx.x;   // 0..383
    int m = blockIdx.y;                        // token 0..2047
    float acc = b_in[n];
    const float* xr = x + m * DMOD;
#pragma unroll 4
    for (int k = 0; k < DMOD; ++k)
        acc = fmaf(xr[k], W_in[k * DI + n], acc);   // xr[k] uniform -> s_load
    h[m * DI + n] = gelu_exact(acc);
}

// K2: per-token dbc = h@W_x+b_x; deltaT/L = softplus(dT/L @ W_dt + b_dt);
//     store deltas + h transposed to (B,DI,H,W); store Bm/Cm token-major.
__global__ void k2_proj(const float* __restrict__ h, const float* __restrict__ W_x,
                        const float* __restrict__ b_x, const float* __restrict__ W_dtT,
                        const float* __restrict__ b_dtT, const float* __restrict__ W_dtL,
                        const float* __restrict__ b_dtL,
                        float* __restrict__ dTt, float* __restrict__ dLt,
                        float* __restrict__ ht, float* __restrict__ BmA,
                        float* __restrict__ CmA) {
    __shared__ float hrow[DI];
    __shared__ float dbc[NCOL];
    int t = threadIdx.x;          // 0..383
    int m = blockIdx.x;           // token
    float hv = h[m * DI + t];
    hrow[t] = hv;
    __syncthreads();
    int wave = t >> 6, lane = t & 63;
    for (int c = wave; c < NCOL; c += 6) {
        float p = 0.f;
        for (int k = lane; k < DI; k += 64) p = fmaf(hrow[k], W_x[k * NCOL + c], p);
        for (int off = 32; off; off >>= 1) p += __shfl_down(p, off, 64);
        if (lane == 0) dbc[c] = p + b_x[c];
    }
    __syncthreads();
    float accT = b_dtT[t], accL = b_dtL[t];
#pragma unroll
    for (int r = 0; r < RK; ++r) {
        accT = fmaf(dbc[r],      W_dtT[r * DI + t], accT);
        accL = fmaf(dbc[RK + r], W_dtL[r * DI + t], accL);
    }
    int b = m >> 10, ij = m & 1023;
    long o = (long)(b * DI + t) * 1024 + ij;
    dTt[o] = softplus_f(accT);
    dLt[o] = softplus_f(accL);
    ht[o]  = hv;
    if (t < DS)            BmA[m * DS + t]        = dbc[2 * RK + t];
    else if (t < 2 * DS)   CmA[m * DS + (t - DS)] = dbc[2 * RK + DS + (t - DS)];
}

// K3: 2D wavefront scan. One block per (b,d): 512 threads = (s in [0,16)) x (j in [0,32)).
// Rows sequential; along j a 5-step segmented inclusive scan via shfl_up(width=32).
// y = gelu(sum_s hs*Cm + h*D) written transposed; yt aliases dTt (row read-before-write).
__global__ __launch_bounds__(512) void k3_scan(
        const float* __restrict__ dTt, const float* __restrict__ dLt,
        const float* __restrict__ ht, const float* __restrict__ BmA,
        const float* __restrict__ CmA, const float* __restrict__ AT_log,
        const float* __restrict__ AL_log, const float* __restrict__ Dv,
        float* __restrict__ yt) {
    __shared__ float ldsB[WW * 17];   // padded [j][s] to avoid 16-way bank conflict
    __shared__ float ldsC[WW * 17];
    __shared__ float red[512];
    int bd = blockIdx.x;            // b*DI + d
    int b = bd / DI, d = bd % DI;
    int tid = threadIdx.x;
    int s = tid >> 5, j = tid & 31;
    float ATv = -expf(AT_log[d * DS + s]);
    float ALv = -expf(AL_log[d * DS + s]);
    float Dd = Dv[d];
    const float* dTrow = dTt + (long)bd * 1024;
    const float* dLrow = dLt + (long)bd * 1024;
    const float* htrow = ht  + (long)bd * 1024;
    float*       ytrow = yt  + (long)bd * 1024;
    const float* Bbase = BmA + (long)b * 1024 * DS;
    const float* Cbase = CmA + (long)b * 1024 * DS;
    float h_prev = 0.f;
    for (int i = 0; i < HH; ++i) {
        {   // stage Bm/Cm row (512 contiguous floats each), transposed into padded LDS
            float bvv = Bbase[i * (WW * DS) + tid];
            float cvv = Cbase[i * (WW * DS) + tid];
            int jj = tid >> 4, ss = tid & 15;
            ldsB[jj * 17 + ss] = bvv;
            ldsC[jj * 17 + ss] = cvv;
        }
        __syncthreads();
        float dTv = dTrow[i * WW + j];
        float dLv = dLrow[i * WW + j];
        float hv  = htrow[i * WW + j];
        float Bv = ldsB[j * 17 + s];
        float Cv = ldsC[j * 17 + s];
        float a = 0.5f * expf(dLv * ALv);
        float u = fmaf(0.5f * expf(dTv * ATv), h_prev,
                       0.5f * (dTv + dLv) * hv * Bv);
#pragma unroll
        for (int off = 1; off < 32; off <<= 1) {
            float au = __shfl_up(a, off, 32);
            float uu = __shfl_up(u, off, 32);
            if (j >= off) { u = fmaf(a, uu, u); a *= au; }
        }
        h_prev = u;                    // full scanned state feeds next row
        red[tid] = u * Cv;
        __syncthreads();
        if (s < 8) red[tid] += red[tid + 8 * 32];
        __syncthreads();
        if (s < 4) red[tid] += red[tid + 4 * 32];
        __syncthreads();
        if (s < 2) red[tid] += red[tid + 2 * 32];
        __syncthreads();
        if (s == 0) {
            float y = red[tid] + red[tid + 32] + hv * Dd;
            ytrow[i * WW + j] = gelu_exact(y);   // overwrites dTt row i AFTER all reads
        }
        __syncthreads();
    }
}

// K4: out = gelu_y @ W_out + b_out.  yt read wave-uniform (scalar loads).
__global__ void k4_outproj(const float* __restrict__ yt, const float* __restrict__ W_out,
                           const float* __restrict__ b_out, float* __restrict__ out) {
    int n = threadIdx.x;       // 0..191
    int m = blockIdx.x;        // token
    int b = m >> 10, ij = m & 1023;
    const float* ycol = yt + (long)b * DI * 1024 + ij;
    float acc = b_out[n];
#pragma unroll 4
    for (int dd = 0; dd < DI; ++dd)
        acc = fmaf(ycol[dd * 1024], W_out[dd * DMOD + n], acc);
    out[m * DMOD + n] = acc;
}

extern "C" void kernel_launch(void* const* d_in, const int* in_sizes, int n_in,
                              void* d_out, int out_size, void* d_ws, size_t ws_size,
                              hipStream_t stream) {
    const float* x      = (const float*)d_in[0];
    const float* W_in   = (const float*)d_in[1];
    const float* b_in   = (const float*)d_in[2];
    const float* W_x    = (const float*)d_in[3];
    const float* b_x    = (const float*)d_in[4];
    const float* W_dtT  = (const float*)d_in[5];
    const float* b_dtT  = (const float*)d_in[6];
    const float* W_dtL  = (const float*)d_in[7];
    const float* b_dtL  = (const float*)d_in[8];
    const float* AT_log = (const float*)d_in[9];
    const float* AL_log = (const float*)d_in[10];
    const float* Dv     = (const float*)d_in[11];
    const float* W_out  = (const float*)d_in[12];
    const float* b_out  = (const float*)d_in[13];
    float* out = (float*)d_out;

    float* ws  = (float*)d_ws;
    float* h   = ws;                 // 786432 f32 (B,H,W,DI) token-major
    float* dTt = ws + 786432;        // (B,DI,H,W)   -- later aliased as yt
    float* dLt = ws + 1572864;       // (B,DI,H,W)
    float* ht  = ws + 2359296;       // (B,DI,H,W)
    float* BmA = ws + 3145728;       // (TOK,DS)
    float* CmA = ws + 3178496;       // (TOK,DS)   total 12.25 MB
    float* yt  = dTt;                // alias: each row read before overwritten in k3

    k1_inproj<<<dim3(3, TOK), 128, 0, stream>>>(x, W_in, b_in, h);
    k2_proj<<<TOK, DI, 0, stream>>>(h, W_x, b_x, W_dtT, b_dtT, W_dtL, b_dtL,
                                    dTt, dLt, ht, BmA, CmA);
    k3_scan<<<BB * DI, 512, 0, stream>>>(dTt, dLt, ht, BmA, CmA,
                                         AT_log, AL_log, Dv, yt);
    k4_outproj<<<TOK, DMOD, 0, stream>>>(yt, W_out, b_out, out);
}

// Round 2
// 244.672 us; speedup vs baseline: 1.1917x; 1.1917x over previous
//
#include <hip/hip_runtime.h>
#include <math.h>

// Problem constants (B=2, H=W=32, DM=192, DS=16, RK=12, DI=384)
#define TOK 2048
#define DMOD 192
#define DI 384
#define DS 16
#define RK 12
#define NCOL 56     // 2*RK + 2*DS
#define HH 32
#define WW 32
#define BB 2
#define TPB 4       // tokens per block in k12 / k4

__device__ __forceinline__ float gelu_exact(float x) {
    return 0.5f * x * (1.0f + erff(x * 0.70710678118654752f));
}
__device__ __forceinline__ float softplus_f(float x) {
    return (x > 20.0f) ? x : log1pf(expf(x));
}

// k0: W_xT[c][k] = W_x[k][c]   (384,56) -> (56,384). Tiny.
__global__ void k0_transWx(const float* __restrict__ W_x, float* __restrict__ W_xT) {
    int c = blockIdx.x;        // 0..55
    int k = threadIdx.x;       // 0..383
    W_xT[c * DI + k] = W_x[k * NCOL + c];
}

// k12: fused in_proj+gelu, x_proj, dt_proj+softplus for 4 tokens per block.
// All stores coalesced token-major.
__global__ __launch_bounds__(DI) void k12_proj(
        const float* __restrict__ x, const float* __restrict__ W_in,
        const float* __restrict__ b_in, const float* __restrict__ W_xT,
        const float* __restrict__ b_x, const float* __restrict__ W_dtT,
        const float* __restrict__ b_dtT, const float* __restrict__ W_dtL,
        const float* __restrict__ b_dtL,
        float* __restrict__ h_tm, float* __restrict__ dT_tm,
        float* __restrict__ dL_tm, float* __restrict__ BmA,
        float* __restrict__ CmA) {
    __shared__ float xr[TPB][DMOD];
    __shared__ float hr[TPB][DI];
    __shared__ float dbcS[TPB][NCOL];
    int t = threadIdx.x;              // 0..383
    int m0 = blockIdx.x * TPB;

    // stage x rows (TPB*192 = 768 floats, 2 per thread, coalesced)
#pragma unroll
    for (int q = 0; q < (TPB * DMOD + DI - 1) / DI; ++q) {
        int idx = q * DI + t;
        if (idx < TPB * DMOD) {
            int tok = idx / DMOD, col = idx - tok * DMOD;
            xr[tok][col] = x[(m0 + tok) * DMOD + col];
        }
    }
    __syncthreads();

    // h = gelu(x @ W_in + b_in); one W_in load feeds TPB tokens
    float hv[TPB];
    {
        float acc[TPB];
        float bi = b_in[t];
#pragma unroll
        for (int tok = 0; tok < TPB; ++tok) acc[tok] = bi;
#pragma unroll 4
        for (int k = 0; k < DMOD; ++k) {
            float w = W_in[k * DI + t];
#pragma unroll
            for (int tok = 0; tok < TPB; ++tok)
                acc[tok] = fmaf(xr[tok][k], w, acc[tok]);
        }
#pragma unroll
        for (int tok = 0; tok < TPB; ++tok) {
            hv[tok] = gelu_exact(acc[tok]);
            hr[tok][t] = hv[tok];
            h_tm[(m0 + tok) * DI + t] = hv[tok];
        }
    }
    __syncthreads();

    // dbc = h @ W_x + b_x : 4*56 = 224 column-jobs over 6 waves
    int wv = t >> 6, ln = t & 63;
    for (int job = wv; job < TPB * NCOL; job += 6) {
        int tok = job / NCOL, c = job - tok * NCOL;
        float p = 0.f;
        const float* wcol = W_xT + c * DI;
#pragma unroll 2
        for (int k = ln; k < DI; k += 64) p = fmaf(hr[tok][k], wcol[k], p);
        for (int off = 32; off; off >>= 1) p += __shfl_down(p, off, 64);
        if (ln == 0) dbcS[tok][c] = p + b_x[c];
    }
    __syncthreads();

    // deltaT/L = softplus(dT/L @ W_dt + bias); coalesced stores
    float accT[TPB], accL[TPB];
    float bT = b_dtT[t], bL = b_dtL[t];
#pragma unroll
    for (int tok = 0; tok < TPB; ++tok) { accT[tok] = bT; accL[tok] = bL; }
#pragma unroll
    for (int r = 0; r < RK; ++r) {
        float wT = W_dtT[r * DI + t];
        float wL = W_dtL[r * DI + t];
#pragma unroll
        for (int tok = 0; tok < TPB; ++tok) {
            accT[tok] = fmaf(dbcS[tok][r],      wT, accT[tok]);
            accL[tok] = fmaf(dbcS[tok][RK + r], wL, accL[tok]);
        }
    }
#pragma unroll
    for (int tok = 0; tok < TPB; ++tok) {
        dT_tm[(m0 + tok) * DI + t] = softplus_f(accT[tok]);
        dL_tm[(m0 + tok) * DI + t] = softplus_f(accL[tok]);
    }
    if (t < 64) {
        int tok = t >> 4, s = t & 15;
        BmA[(m0 + tok) * DS + s] = dbcS[tok][2 * RK + s];
    } else if (t < 128) {
        int tt = t - 64, tok = tt >> 4, s = tt & 15;
        CmA[(m0 + tok) * DS + s] = dbcS[tok][2 * RK + DS + s];
    }
}

// kT: per-b transpose (1024,384) -> (384,1024), 32x32 LDS tiles, both sides coalesced
__global__ void kT_transpose(const float* __restrict__ in, float* __restrict__ out) {
    __shared__ float tile[32][33];
    int ij0 = blockIdx.x * 32, d0 = blockIdx.y * 32, b = blockIdx.z;
    int tx = threadIdx.x, ty = threadIdx.y;
#pragma unroll
    for (int k = 0; k < 4; ++k)
        tile[ty + 8 * k][tx] = in[(b * 1024 + ij0 + ty + 8 * k) * DI + d0 + tx];
    __syncthreads();
#pragma unroll
    for (int k = 0; k < 4; ++k)
        out[(b * DI + d0 + ty + 8 * k) * 1024 + ij0 + tx] = tile[tx][ty + 8 * k];
}

// k3: 2D wavefront scan, ONE WAVE per (b,d). lane = s1*32 + j; 8 s-channels/lane.
// No LDS, no __syncthreads. j-scan via shfl_up(32); s-reduce via shfl_xor(32).
__global__ __launch_bounds__(64) void k3_scan(
        const float* __restrict__ dTt, const float* __restrict__ dLt,
        const float* __restrict__ ht, const float* __restrict__ BmA,
        const float* __restrict__ CmA, const float* __restrict__ AT_log,
        const float* __restrict__ AL_log, const float* __restrict__ Dv,
        float* __restrict__ yt) {
    int bd = blockIdx.x;             // b*DI + d
    int b = bd / DI, d = bd - b * DI;
    int lane = threadIdx.x;
    int j = lane & 31, s1 = lane >> 5;      // s = s1*8 + k

    float AT[8], AL[8];
#pragma unroll
    for (int k = 0; k < 8; ++k) {
        AT[k] = -expf(AT_log[d * DS + s1 * 8 + k]);
        AL[k] = -expf(AL_log[d * DS + s1 * 8 + k]);
    }
    float Dd = Dv[d];

    const float*  dTrow = dTt + (long)bd * 1024;
    const float*  dLrow = dLt + (long)bd * 1024;
    const float*  htrow = ht  + (long)bd * 1024;
    float*        ytrow = yt  + (long)bd * 1024;
    const float4* Bb = (const float4*)(BmA + (long)b * 1024 * DS);
    const float4* Cb = (const float4*)(CmA + (long)b * 1024 * DS);

    float hprev[8];
#pragma unroll
    for (int k = 0; k < 8; ++k) hprev[k] = 0.f;

    // prefetch row 0
    int pidx = j;                       // i*32 + j with i=0
    int pidx4 = j * 4 + s1 * 2;         // float4 index: i*128 + j*4 + s1*2
    float dTv = dTrow[pidx], dLv = dLrow[pidx], hvp = htrow[pidx];
    float4 B0 = Bb[pidx4], B1 = Bb[pidx4 + 1];
    float4 C0 = Cb[pidx4], C1 = Cb[pidx4 + 1];

#pragma unroll 1
    for (int i = 0; i < HH; ++i) {
        float dT_c = dTv, dL_c = dLv, h_c = hvp;
        float Bv[8] = {B0.x, B0.y, B0.z, B0.w, B1.x, B1.y, B1.z, B1.w};
        float Cv[8] = {C0.x, C0.y, C0.z, C0.w, C1.x, C1.y, C1.z, C1.w};
        // prefetch next row (clamped; row 31 re-read harmlessly)
        int inx = (i < HH - 1) ? i + 1 : i;
        int nidx = inx * 32 + j;
        int nidx4 = inx * 128 + j * 4 + s1 * 2;
        dTv = dTrow[nidx]; dLv = dLrow[nidx]; hvp = htrow[nidx];
        B0 = Bb[nidx4]; B1 = Bb[nidx4 + 1];
        C0 = Cb[nidx4]; C1 = Cb[nidx4 + 1];

        float bx = 0.5f * (dT_c + dL_c) * h_c;
        float a[8], u[8];
#pragma unroll
        for (int k = 0; k < 8; ++k) {
            a[k] = 0.5f * __expf(dL_c * AL[k]);
            u[k] = fmaf(0.5f * __expf(dT_c * AT[k]), hprev[k], bx * Bv[k]);
        }
        // inclusive segmented scan along j (width 32), 8 channels
#pragma unroll
        for (int off = 1; off < 32; off <<= 1) {
            float au[8], uu[8];
#pragma unroll
            for (int k = 0; k < 8; ++k) {
                au[k] = __shfl_up(a[k], off, 32);
                uu[k] = __shfl_up(u[k], off, 32);
            }
            if (j >= off) {
#pragma unroll
                for (int k = 0; k < 8; ++k) {
                    u[k] = fmaf(a[k], uu[k], u[k]);
                    a[k] *= au[k];
                }
            }
        }
        float ysum = 0.f;
#pragma unroll
        for (int k = 0; k < 8; ++k) { ysum += u[k] * Cv[k]; hprev[k] = u[k]; }
        ysum += __shfl_xor(ysum, 32, 64);          // add the other 8 s-channels
        if (s1 == 0)
            ytrow[i * 32 + j] = gelu_exact(ysum + h_c * Dd);
    }
}

// k4: out = gelu_y @ W_out + b_out. 4 tokens per block share each W_out load.
__global__ __launch_bounds__(DMOD) void k4_outproj(
        const float* __restrict__ yt, const float* __restrict__ W_out,
        const float* __restrict__ b_out, float* __restrict__ out) {
    int n = threadIdx.x;              // 0..191
    int m0 = blockIdx.x * TPB;
    int b = m0 >> 10, ij0 = m0 & 1023;
    const float* ybase = yt + (long)b * DI * 1024 + ij0;
    float acc[TPB];
    float bo = b_out[n];
#pragma unroll
    for (int tok = 0; tok < TPB; ++tok) acc[tok] = bo;
#pragma unroll 4
    for (int dd = 0; dd < DI; ++dd) {
        float w = W_out[dd * DMOD + n];
        float4 y4 = *(const float4*)(ybase + (long)dd * 1024);   // uniform 16B
        acc[0] = fmaf(y4.x, w, acc[0]);
        acc[1] = fmaf(y4.y, w, acc[1]);
        acc[2] = fmaf(y4.z, w, acc[2]);
        acc[3] = fmaf(y4.w, w, acc[3]);
    }
#pragma unroll
    for (int tok = 0; tok < TPB; ++tok)
        out[(m0 + tok) * DMOD + n] = acc[tok];
}

extern "C" void kernel_launch(void* const* d_in, const int* in_sizes, int n_in,
                              void* d_out, int out_size, void* d_ws, size_t ws_size,
                              hipStream_t stream) {
    const float* x      = (const float*)d_in[0];
    const float* W_in   = (const float*)d_in[1];
    const float* b_in   = (const float*)d_in[2];
    const float* W_x    = (const float*)d_in[3];
    const float* b_x    = (const float*)d_in[4];
    const float* W_dtT  = (const float*)d_in[5];
    const float* b_dtT  = (const float*)d_in[6];
    const float* W_dtL  = (const float*)d_in[7];
    const float* b_dtL  = (const float*)d_in[8];
    const float* AT_log = (const float*)d_in[9];
    const float* AL_log = (const float*)d_in[10];
    const float* Dv     = (const float*)d_in[11];
    const float* W_out  = (const float*)d_in[12];
    const float* b_out  = (const float*)d_in[13];
    float* out = (float*)d_out;

    float* ws = (float*)d_ws;
    const long NE = (long)TOK * DI;     // 786432 per array
    float* buf0 = ws;                   // h_tm  -> later dTT
    float* buf1 = ws + NE;              // dT_tm -> later dLT
    float* buf2 = ws + 2 * NE;          // dL_tm -> later yt
    float* buf3 = ws + 3 * NE;          // hT
    float* BmA  = ws + 4 * NE;          // (TOK,DS)
    float* CmA  = BmA + TOK * DS;
    float* W_xT = CmA + TOK * DS;       // (56,384); total ~12.33 MiB

    k0_transWx<<<NCOL, DI, 0, stream>>>(W_x, W_xT);
    k12_proj<<<TOK / TPB, DI, 0, stream>>>(x, W_in, b_in, W_xT, b_x,
                                           W_dtT, b_dtT, W_dtL, b_dtL,
                                           buf0, buf1, buf2, BmA, CmA);
    dim3 tg(32, 12, 2), tb(32, 8);
    kT_transpose<<<tg, tb, 0, stream>>>(buf0, buf3);   // hT  <- h_tm
    kT_transpose<<<tg, tb, 0, stream>>>(buf1, buf0);   // dTT <- dT_tm
    kT_transpose<<<tg, tb, 0, stream>>>(buf2, buf1);   // dLT <- dL_tm
    k3_scan<<<BB * DI, 64, 0, stream>>>(buf0, buf1, buf3, BmA, CmA,
                                        AT_log, AL_log, Dv, buf2);
    k4_outproj<<<TOK / TPB, DMOD, 0, stream>>>(buf2, W_out, b_out, out);
}

// Round 3
// 223.470 us; speedup vs baseline: 1.3048x; 1.0949x over previous
//
#include <hip/hip_runtime.h>
#include <math.h>

// Problem constants (B=2, H=W=32, DM=192, DS=16, RK=12, DI=384)
#define TOK 2048
#define DMOD 192
#define DI 384
#define DS 16
#define RK 12
#define NCOL 56
#define HH 32
#define WW 32
#define BB 2

__device__ __forceinline__ float gelu_exact(float x) {
    return 0.5f * x * (1.0f + erff(x * 0.70710678118654752f));
}
__device__ __forceinline__ float softplus_f(float x) {
    return (x > 20.0f) ? x : log1pf(expf(x));
}

// K_h: h = gelu(x @ W_in + b_in). 8 tokens/thread, n-tile 128.
// grid (3 n-tiles, 256 m-tiles) x 128 thr.
__global__ __launch_bounds__(128) void K_h(
        const float* __restrict__ x, const float* __restrict__ W_in,
        const float* __restrict__ b_in, float* __restrict__ h_tm) {
    __shared__ float xr[8 * DMOD];     // 8 tokens x 192, flat = contiguous slice of x
    int tx = threadIdx.x;
    int n = blockIdx.x * 128 + tx;
    int m0 = blockIdx.y * 8;
    const float* xs = x + (long)m0 * DMOD;
#pragma unroll
    for (int q = 0; q < 12; ++q) xr[q * 128 + tx] = xs[q * 128 + tx];
    __syncthreads();
    float acc[8];
    float bi = b_in[n];
#pragma unroll
    for (int t = 0; t < 8; ++t) acc[t] = bi;
#pragma unroll 4
    for (int k = 0; k < DMOD; ++k) {
        float w = W_in[k * DI + n];
#pragma unroll
        for (int t = 0; t < 8; ++t)
            acc[t] = fmaf(xr[t * DMOD + k], w, acc[t]);
    }
#pragma unroll
    for (int t = 0; t < 8; ++t)
        h_tm[(long)(m0 + t) * DI + n] = gelu_exact(acc[t]);
}

// K_dbc: dbc = h @ W_x + b_x. One wave per 2 tokens, lane = column (56 of 64).
// Stores dbcT (b, c<24, ij) + BmA/CmA (token-major). No reductions, no LDS.
__global__ __launch_bounds__(256) void K_dbc(
        const float* __restrict__ h_tm, const float* __restrict__ W_x,
        const float* __restrict__ b_x, float* __restrict__ dbcT,
        float* __restrict__ BmA, float* __restrict__ CmA) {
    int tid = threadIdx.x;
    int wid = __builtin_amdgcn_readfirstlane(tid >> 6);   // wave 0..3 (uniform)
    int c = tid & 63;
    int ce = (c < NCOL) ? c : 0;
    int mA = blockIdx.x * 8 + wid * 2;                    // two consecutive tokens
    const float* hA = h_tm + (long)mA * DI;               // uniform base -> s_loads
    const float* hB = hA + DI;
    const float* Wp = W_x + ce;
    float a0 = 0.f, a1 = 0.f, b0 = 0.f, b1 = 0.f;
#pragma unroll 2
    for (int k = 0; k < DI; k += 4) {
        float w0 = Wp[(k + 0) * NCOL], w1 = Wp[(k + 1) * NCOL];
        float w2 = Wp[(k + 2) * NCOL], w3 = Wp[(k + 3) * NCOL];
        a0 = fmaf(hA[k + 0], w0, a0);  a1 = fmaf(hA[k + 1], w1, a1);
        a0 = fmaf(hA[k + 2], w2, a0);  a1 = fmaf(hA[k + 3], w3, a1);
        b0 = fmaf(hB[k + 0], w0, b0);  b1 = fmaf(hB[k + 1], w1, b1);
        b0 = fmaf(hB[k + 2], w2, b0);  b1 = fmaf(hB[k + 3], w3, b1);
    }
    float dvA = a0 + a1 + b_x[ce];
    float dvB = b0 + b1 + b_x[ce];
    int b = mA >> 10, ijA = mA & 1023;
    if (c < 2 * RK) {                       // dT/dL ranks, transposed store
        long o = (long)(b * 24 + c) * 1024 + ijA;
        dbcT[o] = dvA;  dbcT[o + 1] = dvB;
    } else if (c < 2 * RK + DS) {           // Bm
        int s = c - 2 * RK;
        BmA[(long)mA * DS + s] = dvA;  BmA[(long)(mA + 1) * DS + s] = dvB;
    } else if (c < NCOL) {                  // Cm
        int s = c - 2 * RK - DS;
        CmA[(long)mA * DS + s] = dvA;  CmA[(long)(mA + 1) * DS + s] = dvB;
    }
}

// kT: token-major (b,1024,384) -> d-major (b,384,1024)
__global__ void kT_fwd(const float* __restrict__ in, float* __restrict__ out) {
    __shared__ float tile[32][33];
    int ij0 = blockIdx.x * 32, d0 = blockIdx.y * 32, b = blockIdx.z;
    int tx = threadIdx.x, ty = threadIdx.y;
#pragma unroll
    for (int k = 0; k < 4; ++k)
        tile[ty + 8 * k][tx] = in[(long)(b * 1024 + ij0 + ty + 8 * k) * DI + d0 + tx];
    __syncthreads();
#pragma unroll
    for (int k = 0; k < 4; ++k)
        out[(long)(b * DI + d0 + ty + 8 * k) * 1024 + ij0 + tx] = tile[tx][ty + 8 * k];
}

// kT_back: d-major (b,384,1024) -> token-major (b,1024,384)
__global__ void kT_back(const float* __restrict__ in, float* __restrict__ out) {
    __shared__ float tile[32][33];
    int ij0 = blockIdx.x * 32, d0 = blockIdx.y * 32, b = blockIdx.z;
    int tx = threadIdx.x, ty = threadIdx.y;
#pragma unroll
    for (int k = 0; k < 4; ++k)
        tile[ty + 8 * k][tx] = in[(long)(b * DI + d0 + ty + 8 * k) * 1024 + ij0 + tx];
    __syncthreads();
#pragma unroll
    for (int k = 0; k < 4; ++k)
        out[(long)(b * 1024 + ij0 + ty + 8 * k) * DI + d0 + tx] = tile[tx][ty + 8 * k];
}

// k3: 2D wavefront scan + inline dt_proj/softplus. One block per (b,d),
// 4 waves, s split 4 ways (2 channels/lane). lane = s1*32+j; p = w*2+s1.
__global__ __launch_bounds__(256) void k3_scan(
        const float* __restrict__ hT, const float* __restrict__ dbcT,
        const float* __restrict__ BmA, const float* __restrict__ CmA,
        const float* __restrict__ W_dtT, const float* __restrict__ b_dtT,
        const float* __restrict__ W_dtL, const float* __restrict__ b_dtL,
        const float* __restrict__ AT_log, const float* __restrict__ AL_log,
        const float* __restrict__ Dv, float* __restrict__ yt) {
    __shared__ float dbcS[2][24][32];
    __shared__ float red[2][4][32];
    int bd = blockIdx.x;
    int b = bd / DI, d = bd - b * DI;
    int tid = threadIdx.x;
    int w = tid >> 6, lane = tid & 63;
    int s1 = lane >> 5, j = lane & 31;
    int p = w * 2 + s1;                         // s-pair 0..7 -> s = 2p, 2p+1

    float wT[RK], wL[RK];
#pragma unroll
    for (int r = 0; r < RK; ++r) {
        wT[r] = W_dtT[r * DI + d];
        wL[r] = W_dtL[r * DI + d];
    }
    float bT = b_dtT[d], bL = b_dtL[d], Dd = Dv[d];
    float AT0 = -expf(AT_log[d * DS + 2 * p]);
    float AT1 = -expf(AT_log[d * DS + 2 * p + 1]);
    float AL0 = -expf(AL_log[d * DS + 2 * p]);
    float AL1 = -expf(AL_log[d * DS + 2 * p + 1]);

    const float*  hrow = hT + (long)bd * 1024;
    float*        yrow = yt + (long)bd * 1024;
    const float2* Bb = (const float2*)(BmA + (long)b * 1024 * DS);
    const float2* Cb = (const float2*)(CmA + (long)b * 1024 * DS);
    const float*  dbase = dbcT + (long)b * 24 * 1024;

    // prefetch row 0
    float hv_n = hrow[j];
    float2 Bn = Bb[j * 8 + p], Cn = Cb[j * 8 + p];
#pragma unroll
    for (int q = 0; q < 3; ++q) {
        int cc = w * 6 + q * 2 + s1;
        dbcS[0][cc][j] = dbase[(long)cc * 1024 + j];
    }
    __syncthreads();

    float hp0 = 0.f, hp1 = 0.f;
#pragma unroll 1
    for (int i = 0; i < HH; ++i) {
        int cur = i & 1, nxt = cur ^ 1;
        float hc = hv_n;
        float2 Bv = Bn, Cv = Cn;
        // deltaT/deltaL from dbc (broadcast LDS reads)
        float aT = bT, aL = bL;
#pragma unroll
        for (int r = 0; r < RK; ++r) {
            aT = fmaf(dbcS[cur][r][j],      wT[r], aT);
            aL = fmaf(dbcS[cur][RK + r][j], wL[r], aL);
        }
        float dTv = softplus_f(aT), dLv = softplus_f(aL);
        // prefetch row i+1
        if (i < HH - 1) {
            int off = (i + 1) * 32 + j;
            hv_n = hrow[off];
            Bn = Bb[off * 8 + p];  Cn = Cb[off * 8 + p];
#pragma unroll
            for (int q = 0; q < 3; ++q) {
                int cc = w * 6 + q * 2 + s1;
                dbcS[nxt][cc][j] = dbase[(long)cc * 1024 + off];
            }
        }
        float bx = 0.5f * (dTv + dLv) * hc;
        float a0 = 0.5f * __expf(dLv * AL0);
        float a1 = 0.5f * __expf(dLv * AL1);
        float u0 = fmaf(0.5f * __expf(dTv * AT0), hp0, bx * Bv.x);
        float u1 = fmaf(0.5f * __expf(dTv * AT1), hp1, bx * Bv.y);
#pragma unroll
        for (int of = 1; of < 32; of <<= 1) {
            float a0u = __shfl_up(a0, of, 32);
            float u0u = __shfl_up(u0, of, 32);
            float a1u = __shfl_up(a1, of, 32);
            float u1u = __shfl_up(u1, of, 32);
            if (j >= of) {
                u0 = fmaf(a0, u0u, u0);  a0 *= a0u;
                u1 = fmaf(a1, u1u, u1);  a1 *= a1u;
            }
        }
        hp0 = u0;  hp1 = u1;
        float part = u0 * Cv.x + u1 * Cv.y;
        part += __shfl_xor(part, 32, 64);        // combine the two s1 halves
        if (s1 == 0) red[cur][w][j] = part;
        __syncthreads();
        if (w == 0 && s1 == 0) {
            float y = red[cur][0][j] + red[cur][1][j] + red[cur][2][j] +
                      red[cur][3][j] + hc * Dd;
            yrow[i * 32 + j] = gelu_exact(y);
        }
    }
}

// K_out: out = y @ W_out + b_out. 4 tokens/thread, block = 192 (n).
__global__ __launch_bounds__(DMOD) void K_out(
        const float* __restrict__ y_tm, const float* __restrict__ W_out,
        const float* __restrict__ b_out, float* __restrict__ out) {
    __shared__ float ys[4 * DI];     // 4 tokens x 384, flat contiguous
    int tx = threadIdx.x;
    int m0 = blockIdx.x * 4;
    const float* yb = y_tm + (long)m0 * DI;
#pragma unroll
    for (int q = 0; q < 8; ++q) ys[q * DMOD + tx] = yb[q * DMOD + tx];
    __syncthreads();
    float acc[4];
    float bo = b_out[tx];
#pragma unroll
    for (int t = 0; t < 4; ++t) acc[t] = bo;
#pragma unroll 4
    for (int dd = 0; dd < DI; ++dd) {
        float w = W_out[dd * DMOD + tx];
#pragma unroll
        for (int t = 0; t < 4; ++t)
            acc[t] = fmaf(ys[t * DI + dd], w, acc[t]);
    }
#pragma unroll
    for (int t = 0; t < 4; ++t)
        out[(long)(m0 + t) * DMOD + tx] = acc[t];
}

extern "C" void kernel_launch(void* const* d_in, const int* in_sizes, int n_in,
                              void* d_out, int out_size, void* d_ws, size_t ws_size,
                              hipStream_t stream) {
    const float* x      = (const float*)d_in[0];
    const float* W_in   = (const float*)d_in[1];
    const float* b_in   = (const float*)d_in[2];
    const float* W_x    = (const float*)d_in[3];
    const float* b_x    = (const float*)d_in[4];
    const float* W_dtT  = (const float*)d_in[5];
    const float* b_dtT  = (const float*)d_in[6];
    const float* W_dtL  = (const float*)d_in[7];
    const float* b_dtL  = (const float*)d_in[8];
    const float* AT_log = (const float*)d_in[9];
    const float* AL_log = (const float*)d_in[10];
    const float* Dv     = (const float*)d_in[11];
    const float* W_out  = (const float*)d_in[12];
    const float* b_out  = (const float*)d_in[13];
    float* out = (float*)d_out;

    float* ws = (float*)d_ws;
    const long NE = (long)TOK * DI;        // 786432
    float* h_tm = ws;                      // (b, ij, 384)
    float* hT   = ws + NE;                 // (b, 384, ij)
    float* dbcT = ws + 2 * NE;             // (b, 24, 1024) = 49152
    float* BmA  = dbcT + 49152;            // (tok, 16)
    float* CmA  = BmA + TOK * DS;          // (tok, 16)   total ~6.44 MB
    float* yt   = h_tm;                    // alias: h_tm dead after kT_fwd
    float* y_tm = hT;                      // alias: hT dead after k3_scan

    K_h<<<dim3(3, 256), 128, 0, stream>>>(x, W_in, b_in, h_tm);
    K_dbc<<<256, 256, 0, stream>>>(h_tm, W_x, b_x, dbcT, BmA, CmA);
    kT_fwd<<<dim3(32, 12, 2), dim3(32, 8), 0, stream>>>(h_tm, hT);
    k3_scan<<<BB * DI, 256, 0, stream>>>(hT, dbcT, BmA, CmA,
                                         W_dtT, b_dtT, W_dtL, b_dtL,
                                         AT_log, AL_log, Dv, yt);
    kT_back<<<dim3(32, 12, 2), dim3(32, 8), 0, stream>>>(yt, y_tm);
    K_out<<<TOK / 4, DMOD, 0, stream>>>(y_tm, W_out, b_out, out);
}

// Round 4
// 177.794 us; speedup vs baseline: 1.6399x; 1.2569x over previous
//
#include <hip/hip_runtime.h>
#include <math.h>

// Problem constants (B=2, H=W=32, DM=192, DS=16, RK=12, DI=384)
#define TOK 2048
#define DMOD 192
#define DI 384
#define DS 16
#define RK 12
#define NCOL 56
#define HH 32
#define WW 32
#define BB 2
#define TA 8          // tokens per K_A / K_out block
#define HSP 388       // padded hs row (388%4==0 keeps b128 alignment)

__device__ __forceinline__ float gelu_exact(float x) {
    return 0.5f * x * (1.0f + erff(x * 0.70710678118654752f));
}
__device__ __forceinline__ float softplus_f(float x) {
    return (x > 20.0f) ? x : log1pf(expf(x));
}
__device__ __forceinline__ float bperm(int byte_addr, float v) {
    return __uint_as_float((unsigned)__builtin_amdgcn_ds_bpermute(
        byte_addr, (int)__float_as_uint(v)));
}

// k0: W_xT[c][k] = W_x[k][c]   (384,56) -> (56,384). Tiny.
__global__ void k0_transWx(const float* __restrict__ W_x, float* __restrict__ W_xT) {
    int c = blockIdx.x, k = threadIdx.x;
    W_xT[c * DI + k] = W_x[k * NCOL + c];
}

// K_A: per 8 tokens: h=gelu(x@W_in+b) ; dbc=h@W_x+b ; delta=softplus(dbc@W_dt+b).
// Stores h/dT/dL d-major (contiguous 8-token chunks), Bm/Cm s-major.
__global__ __launch_bounds__(DI) void K_A(
        const float* __restrict__ x, const float* __restrict__ W_in,
        const float* __restrict__ b_in, const float* __restrict__ W_xT,
        const float* __restrict__ b_x, const float* __restrict__ W_dtT,
        const float* __restrict__ b_dtT, const float* __restrict__ W_dtL,
        const float* __restrict__ b_dtL,
        float* __restrict__ ht, float* __restrict__ dTt, float* __restrict__ dLt,
        float* __restrict__ Bs, float* __restrict__ Cs) {
    __shared__ float xs[TA * DMOD];       // 6 KB
    __shared__ float hs[TA * HSP];        // 12.4 KB (padded rows)
    __shared__ float dbcS[TA][NCOL];      // 1.8 KB
    int tid = threadIdx.x;
    int tok0 = blockIdx.x * TA;

    const float* xg = x + (long)tok0 * DMOD;
#pragma unroll
    for (int q = 0; q < 4; ++q) xs[q * DI + tid] = xg[q * DI + tid];
    __syncthreads();

    // phase 1: h (thread = n, 8 token accumulators)
    float acc[TA];
    float bi = b_in[tid];
#pragma unroll
    for (int t = 0; t < TA; ++t) acc[t] = bi;
    for (int k = 0; k < DMOD; k += 4) {
        float w0 = W_in[(k + 0) * DI + tid];
        float w1 = W_in[(k + 1) * DI + tid];
        float w2 = W_in[(k + 2) * DI + tid];
        float w3 = W_in[(k + 3) * DI + tid];
#pragma unroll
        for (int t = 0; t < TA; ++t) {
            float4 xv = *(const float4*)&xs[t * DMOD + k];
            acc[t] = fmaf(xv.x, w0, acc[t]);
            acc[t] = fmaf(xv.y, w1, acc[t]);
            acc[t] = fmaf(xv.z, w2, acc[t]);
            acc[t] = fmaf(xv.w, w3, acc[t]);
        }
    }
#pragma unroll
    for (int t = 0; t < TA; ++t) hs[t * HSP + tid] = gelu_exact(acc[t]);
    __syncthreads();

    // phase 2: dbc (448 outputs over 384 threads; rows/cols vectorized by 4)
    for (int oi = tid; oi < TA * NCOL; oi += DI) {
        int tk = oi / NCOL, c = oi - tk * NCOL;
        float p = b_x[c];
        const float* hrow = &hs[tk * HSP];
        const float4* wr = (const float4*)(W_xT + c * DI);
        for (int k = 0; k < DI; k += 4) {
            float4 hv = *(const float4*)&hrow[k];
            float4 wv = wr[k >> 2];
            p = fmaf(hv.x, wv.x, p);  p = fmaf(hv.y, wv.y, p);
            p = fmaf(hv.z, wv.z, p);  p = fmaf(hv.w, wv.w, p);
        }
        dbcS[tk][c] = p;
    }
    __syncthreads();

    // phase 3: deltas (thread = d), then d-major stores
    int d = tid;
    float aT[TA], aL[TA];
    float bT = b_dtT[d], bL = b_dtL[d];
#pragma unroll
    for (int t = 0; t < TA; ++t) { aT[t] = bT; aL[t] = bL; }
#pragma unroll
    for (int r = 0; r < RK; ++r) {
        float wT = W_dtT[r * DI + d];
        float wL = W_dtL[r * DI + d];
#pragma unroll
        for (int t = 0; t < TA; ++t) {
            aT[t] = fmaf(dbcS[t][r],      wT, aT[t]);
            aL[t] = fmaf(dbcS[t][RK + r], wL, aL[t]);
        }
    }
    int b = tok0 >> 10;
    long ob = (long)(b * DI + d) * 1024 + (tok0 & 1023);
    float v[TA];
#pragma unroll
    for (int t = 0; t < TA; ++t) v[t] = softplus_f(aT[t]);
    *(float4*)&dTt[ob]     = make_float4(v[0], v[1], v[2], v[3]);
    *(float4*)&dTt[ob + 4] = make_float4(v[4], v[5], v[6], v[7]);
#pragma unroll
    for (int t = 0; t < TA; ++t) v[t] = softplus_f(aL[t]);
    *(float4*)&dLt[ob]     = make_float4(v[0], v[1], v[2], v[3]);
    *(float4*)&dLt[ob + 4] = make_float4(v[4], v[5], v[6], v[7]);
#pragma unroll
    for (int t = 0; t < TA; ++t) v[t] = hs[t * HSP + d];
    *(float4*)&ht[ob]     = make_float4(v[0], v[1], v[2], v[3]);
    *(float4*)&ht[ob + 4] = make_float4(v[4], v[5], v[6], v[7]);
    if (tid < 128) {                       // Bm/Cm s-major
        int s = tid >> 3, tt = tid & 7;
        long o = (long)(b * DS + s) * 1024 + (tok0 & 1023) + tt;
        Bs[o] = dbcS[tt][2 * RK + s];
        Cs[o] = dbcS[tt][2 * RK + DS + s];
    }
}

// k3: 2D wavefront scan. Block per (b,d); 4 waves; lane=(s1,j); 2 s-channels/lane.
// Barrier-free main loop (state is lane-local); one final barrier + y pass.
__global__ __launch_bounds__(256) void k3_scan(
        const float* __restrict__ dTt, const float* __restrict__ dLt,
        const float* __restrict__ ht, const float* __restrict__ Bs,
        const float* __restrict__ Cs, const float* __restrict__ AT_log,
        const float* __restrict__ AL_log, const float* __restrict__ Dv,
        float* __restrict__ yt) {
    __shared__ float part[8][HH][WW];      // 32 KB
    int bd = blockIdx.x;
    int b = bd / DI, d = bd - b * DI;
    int tid = threadIdx.x;
    int w = tid >> 6, lane = tid & 63;
    int s1 = lane >> 5, j = lane & 31;
    int p = w * 2 + s1;                    // s-pair -> s = 2p, 2p+1

    float AT0 = -__expf(AT_log[d * DS + 2 * p]);
    float AT1 = -__expf(AT_log[d * DS + 2 * p + 1]);
    float AL0 = -__expf(AL_log[d * DS + 2 * p]);
    float AL1 = -__expf(AL_log[d * DS + 2 * p + 1]);

    const float* dTr = dTt + (long)bd * 1024;
    const float* dLr = dLt + (long)bd * 1024;
    const float* hr  = ht  + (long)bd * 1024;
    const float* B0r = Bs + (long)(b * DS + 2 * p) * 1024;
    const float* B1r = B0r + 1024;
    const float* C0r = Cs + (long)(b * DS + 2 * p) * 1024;
    const float* C1r = C0r + 1024;

    // precomputed bpermute byte addresses (self for j<off; fixed by cndmask)
    int ba1  = ((j >= 1  ? lane - 1  : lane) << 2);
    int ba2  = ((j >= 2  ? lane - 2  : lane) << 2);
    int ba4  = ((j >= 4  ? lane - 4  : lane) << 2);
    int ba8  = ((j >= 8  ? lane - 8  : lane) << 2);
    int ba16 = ((j >= 16 ? lane - 16 : lane) << 2);

    float hp0 = 0.f, hp1 = 0.f;
    float nT = dTr[j], nL = dLr[j], nh = hr[j];
    float nB0 = B0r[j], nB1 = B1r[j], nC0 = C0r[j], nC1 = C1r[j];

#pragma unroll 1
    for (int i = 0; i < HH; ++i) {
        float cT = nT, cL = nL, chv = nh;
        float cB0 = nB0, cB1 = nB1, cC0 = nC0, cC1 = nC1;
        int nx = (i + 1 < HH) ? (i + 1) * 32 + j : j;   // clamped prefetch
        nT = dTr[nx]; nL = dLr[nx]; nh = hr[nx];
        nB0 = B0r[nx]; nB1 = B1r[nx]; nC0 = C0r[nx]; nC1 = C1r[nx];

        float g  = 0.5f * (cT + cL) * chv;
        float a0 = 0.5f * __expf(cL * AL0);
        float a1 = 0.5f * __expf(cL * AL1);
        float u0 = fmaf(0.5f * __expf(cT * AT0), hp0, g * cB0);
        float u1 = fmaf(0.5f * __expf(cT * AT1), hp1, g * cB1);

#define SCAN_STEP(BA, OFF)                                            \
        {                                                             \
            float au0 = bperm(BA, a0), uu0 = bperm(BA, u0);           \
            float au1 = bperm(BA, a1), uu1 = bperm(BA, u1);           \
            bool m = (j >= OFF);                                      \
            uu0 = m ? uu0 : 0.f;  au0 = m ? au0 : 1.f;                \
            uu1 = m ? uu1 : 0.f;  au1 = m ? au1 : 1.f;                \
            u0 = fmaf(a0, uu0, u0);  a0 *= au0;                       \
            u1 = fmaf(a1, uu1, u1);  a1 *= au1;                       \
        }
        SCAN_STEP(ba1, 1)  SCAN_STEP(ba2, 2)  SCAN_STEP(ba4, 4)
        SCAN_STEP(ba8, 8)  SCAN_STEP(ba16, 16)
#undef SCAN_STEP

        hp0 = u0;  hp1 = u1;
        part[p][i][j] = fmaf(u0, cC0, u1 * cC1);
    }
    __syncthreads();

    float Dd = Dv[d];
    float* yr = yt + (long)bd * 1024;
#pragma unroll
    for (int q = 0; q < 4; ++q) {
        int cell = q * 256 + tid;
        float sum = part[0][0][cell] + part[1][0][cell] + part[2][0][cell] +
                    part[3][0][cell] + part[4][0][cell] + part[5][0][cell] +
                    part[6][0][cell] + part[7][0][cell];
        yr[cell] = gelu_exact(sum + hr[cell] * Dd);
    }
}

// K_out: out = y @ W_out + b_out. y read d-major via wave-uniform float4 (s_load);
// 8 tokens/thread amortize W_out reads.
__global__ __launch_bounds__(DMOD) void K_out(
        const float* __restrict__ yt, const float* __restrict__ W_out,
        const float* __restrict__ b_out, float* __restrict__ out) {
    int n = threadIdx.x;
    int tok0 = blockIdx.x * TA;
    int b = tok0 >> 10;
    const float* yb = yt + (long)b * DI * 1024 + (tok0 & 1023);
    float acc[TA];
    float bo = b_out[n];
#pragma unroll
    for (int t = 0; t < TA; ++t) acc[t] = bo;
    for (int dd = 0; dd < DI; ++dd) {
        float w = W_out[dd * DMOD + n];
        const float* yp = yb + (long)dd * 1024;
        float4 y0 = *(const float4*)yp;
        float4 y1 = *(const float4*)(yp + 4);
        acc[0] = fmaf(y0.x, w, acc[0]);  acc[1] = fmaf(y0.y, w, acc[1]);
        acc[2] = fmaf(y0.z, w, acc[2]);  acc[3] = fmaf(y0.w, w, acc[3]);
        acc[4] = fmaf(y1.x, w, acc[4]);  acc[5] = fmaf(y1.y, w, acc[5]);
        acc[6] = fmaf(y1.z, w, acc[6]);  acc[7] = fmaf(y1.w, w, acc[7]);
    }
#pragma unroll
    for (int t = 0; t < TA; ++t)
        out[(long)(tok0 + t) * DMOD + n] = acc[t];
}

extern "C" void kernel_launch(void* const* d_in, const int* in_sizes, int n_in,
                              void* d_out, int out_size, void* d_ws, size_t ws_size,
                              hipStream_t stream) {
    const float* x      = (const float*)d_in[0];
    const float* W_in   = (const float*)d_in[1];
    const float* b_in   = (const float*)d_in[2];
    const float* W_x    = (const float*)d_in[3];
    const float* b_x    = (const float*)d_in[4];
    const float* W_dtT  = (const float*)d_in[5];
    const float* b_dtT  = (const float*)d_in[6];
    const float* W_dtL  = (const float*)d_in[7];
    const float* b_dtL  = (const float*)d_in[8];
    const float* AT_log = (const float*)d_in[9];
    const float* AL_log = (const float*)d_in[10];
    const float* Dv     = (const float*)d_in[11];
    const float* W_out  = (const float*)d_in[12];
    const float* b_out  = (const float*)d_in[13];
    float* out = (float*)d_out;

    float* ws = (float*)d_ws;
    const long NE = (long)BB * DI * 1024;     // 786432 per d-major array
    float* ht   = ws;                          // (b, d, ij)
    float* dTt  = ws + NE;                     // (b, d, ij)  -- later aliased as yt
    float* dLt  = ws + 2 * NE;                 // (b, d, ij)
    float* Bs   = ws + 3 * NE;                 // (b, s, ij) s-major
    float* Cs   = Bs + (long)BB * DS * 1024;
    float* W_xT = Cs + (long)BB * DS * 1024;   // (56,384); total ~9.8 MB
    float* yt   = dTt;   // alias: all dTt reads precede the post-barrier y writes

    k0_transWx<<<NCOL, DI, 0, stream>>>(W_x, W_xT);
    K_A<<<TOK / TA, DI, 0, stream>>>(x, W_in, b_in, W_xT, b_x,
                                     W_dtT, b_dtT, W_dtL, b_dtL,
                                     ht, dTt, dLt, Bs, Cs);
    k3_scan<<<BB * DI, 256, 0, stream>>>(dTt, dLt, ht, Bs, Cs,
                                         AT_log, AL_log, Dv, yt);
    K_out<<<TOK / TA, DMOD, 0, stream>>>(yt, W_out, b_out, out);
}